// Round 5
// baseline (179.614 us; speedup 1.0000x reference)
//
#include <hip/hip_runtime.h>
#include <cstddef>

#define B_   8
#define H_   96
#define W_   96
#define HW_  9216
#define PIX_ 73728

typedef __attribute__((ext_vector_type(8))) __bf16 bf16x8;
typedef __attribute__((ext_vector_type(4))) float floatx4;

// ws layout (byte offsets)
#define XT_OFF   0                          // bf16 NHWC x: PIX*64*2
#define WFM_OFF  (XT_OFF + PIX_*64*2)       // main W frags: 18*4*64*8 bf16
#define WFO_OFF  (WFM_OFF + 18*4*64*8*2)    // offs W frags: 18*2*64*8 bf16

#define MSTR 76                             // meta LDS stride per pixel (floats)

__device__ __forceinline__ unsigned short f2bf(float f) {
    unsigned u = __float_as_uint(f);
    return (unsigned short)((u + 0x7FFFu + ((u >> 16) & 1u)) >> 16);
}

// ---------------------------------------------------------------------------
// Fused pre-pass: blocks [0,1152) transpose NCHW f32 -> NHWC bf16 (vectorized);
// blocks [1152,1179) pack MFMA A-fragments.
__global__ __launch_bounds__(256) void k_pre(const float* __restrict__ x,
                                             const float* __restrict__ offw,
                                             const float* __restrict__ mw,
                                             const float* __restrict__ convw,
                                             unsigned short* __restrict__ xt,
                                             unsigned short* __restrict__ wfm,
                                             unsigned short* __restrict__ wfo) {
    __shared__ float tile[64 * 68];
    int blk = blockIdx.x;
    int t = threadIdx.x;
    if (blk < 1152) {
        int bb  = blk / 144;
        int sp0 = (blk % 144) * 64;
        int cL = t >> 4;               // 0..15
        int s4 = (t & 15) * 4;         // 0..60
        #pragma unroll
        for (int i = 0; i < 4; ++i) {
            int c = cL + i * 16;
            float4 v = *(const float4*)&x[(size_t)(bb * 64 + c) * HW_ + sp0 + s4];
            *(float4*)&tile[c * 68 + s4] = v;
        }
        __syncthreads();
        int s2 = t >> 2;               // 0..63
        int cg = (t & 3) * 16;         // 0,16,32,48
        unsigned vv[8];
        #pragma unroll
        for (int j = 0; j < 8; ++j) {
            float f0 = tile[(cg + 2 * j) * 68 + s2];
            float f1 = tile[(cg + 2 * j + 1) * 68 + s2];
            vv[j] = (unsigned)f2bf(f0) | ((unsigned)f2bf(f1) << 16);
        }
        uint4 p0 = make_uint4(vv[0], vv[1], vv[2], vv[3]);
        uint4 p1 = make_uint4(vv[4], vv[5], vv[6], vv[7]);
        unsigned short* dst = xt + (size_t)(bb * HW_ + sp0 + s2) * 64 + cg;
        *(uint4*)dst = p0;
        *(uint4*)(dst + 8) = p1;
        return;
    }
    int g = (blk - 1152) * 256 + t;
    if (g < 4608) {
        int lane = g & 63, mtks = g >> 6;
        int mt = mtks & 3, ks = mtks >> 2;
        int o = mt * 16 + (lane & 15), quad = lane >> 4;
        unsigned v[8];
        #pragma unroll
        for (int j = 0; j < 8; ++j) {
            int k = ks * 32 + quad * 8 + j;
            int tt = k / 64, c = k % 64;
            v[j] = f2bf(convw[(size_t)(o * 64 + c) * 9 + tt]);
        }
        uint4 pk;
        pk.x = v[0] | (v[1] << 16); pk.y = v[2] | (v[3] << 16);
        pk.z = v[4] | (v[5] << 16); pk.w = v[6] | (v[7] << 16);
        *(uint4*)(wfm + (size_t)g * 8) = pk;
    } else if (g < 4608 + 2304) {
        int g2 = g - 4608;
        int lane = g2 & 63, mtks = g2 >> 6;
        int mt = mtks & 1, ks = mtks >> 1;
        int m = mt * 16 + (lane & 15), quad = lane >> 4;
        unsigned v[8];
        #pragma unroll
        for (int j = 0; j < 8; ++j) {
            int k = ks * 32 + quad * 8 + j;
            int tt = k / 64, c = k % 64;
            float f = 0.f;
            if (m < 18)      f = offw[(size_t)(m * 64 + c) * 9 + tt];
            else if (m < 27) f = mw[(size_t)((m - 18) * 64 + c) * 9 + tt];
            v[j] = f2bf(f);
        }
        uint4 pk;
        pk.x = v[0] | (v[1] << 16); pk.y = v[2] | (v[3] << 16);
        pk.z = v[4] | (v[5] << 16); pk.w = v[6] | (v[7] << 16);
        *(uint4*)(wfo + (size_t)g2 * 8) = pk;
    }
}

// ---------------------------------------------------------------------------
// Fused deform-conv. One wave owns 16 pixels; waves fully independent
// (per-wave LDS, wave-synchronous handoff, NO __syncthreads).
// Phase 3 feeds raw gathered corners to MFMA (K=64 per tap per corner) and
// applies bilinear weights to the f32 MFMA output per-lane.
__global__ __launch_bounds__(128, 4) void k_fused(const unsigned short* __restrict__ xt,
                                                  const unsigned short* __restrict__ wfo,
                                                  const unsigned short* __restrict__ wfm,
                                                  const float* __restrict__ offb,
                                                  const float* __restrict__ mb,
                                                  const float* __restrict__ convb,
                                                  float* __restrict__ out) {
    __shared__ float s_off[2][32 * 17];     // [wave][m][pix16] (+1 pad)
    __shared__ float s_meta[2][16 * MSTR];  // [wave][pix][n*8 words]
    int tid = threadIdx.x, blk = blockIdx.x;
    int w = tid >> 6, lane = tid & 63, col = lane & 15, quad = lane >> 4;
    int q8 = quad * 8;
    int b  = blk / 288;                     // 288 blocks (32 px each) per batch
    int sb = (blk % 288) * 32 + w * 16;
    const unsigned short* xtb = xt + (size_t)b * HW_ * 64;
    int sp = sb + col, hh = sp / 96, ww = sp % 96;

    // ---- phase 1: offset/mod conv GEMM (M=32, K=576, N=16) ----
    floatx4 aoff0 = {0.f, 0.f, 0.f, 0.f}, aoff1 = {0.f, 0.f, 0.f, 0.f};
    #pragma unroll 1
    for (int t = 0; t < 9; ++t) {
        int dh = t / 3 - 1, dw = t % 3 - 1;
        int h2 = hh + dh, w2 = ww + dw;
        bool ok = ((unsigned)h2 < 96u) && ((unsigned)w2 < 96u);
        const unsigned short* pb = xtb + ((size_t)(h2 * 96 + w2) * 64 + q8);
        uint4 bv[2];
        bv[0] = ok ? *(const uint4*)(pb)      : make_uint4(0, 0, 0, 0);
        bv[1] = ok ? *(const uint4*)(pb + 32) : make_uint4(0, 0, 0, 0);
        #pragma unroll
        for (int ksl = 0; ksl < 2; ++ksl) {
            int ks = t * 2 + ksl;
            bf16x8 a0 = *(const bf16x8*)(wfo + ((size_t)(ks * 2 + 0) * 64 + lane) * 8);
            bf16x8 a1 = *(const bf16x8*)(wfo + ((size_t)(ks * 2 + 1) * 64 + lane) * 8);
            union { uint4 u; bf16x8 b; } uu; uu.u = bv[ksl];
            aoff0 = __builtin_amdgcn_mfma_f32_16x16x32_bf16(a0, uu.b, aoff0, 0, 0, 0);
            aoff1 = __builtin_amdgcn_mfma_f32_16x16x32_bf16(a1, uu.b, aoff1, 0, 0, 0);
        }
    }
    #pragma unroll
    for (int r = 0; r < 4; ++r) {
        s_off[w][(quad * 4 + r) * 17 + col]        = aoff0[r];
        s_off[w][(16 + quad * 4 + r) * 17 + col]   = aoff1[r];
    }
    __builtin_amdgcn_wave_barrier();

    // ---- phase 2: bilinear metadata (wave-local; lane covers px=col, n set by quad) ----
    #pragma unroll
    for (int i = 0; i < 3; ++i) {
        int n = quad + 4 * i;
        if (n <= 8) {
            float ox = s_off[w][n * 17 + col]        + offb[n];
            float oy = s_off[w][(9 + n) * 17 + col]  + offb[9 + n];
            float mv = s_off[w][(18 + n) * 17 + col] + mb[n];
            float mod = 1.f / (1.f + __expf(-mv));
            float px = ox + (float)(hh + 1) + (float)(n / 3 - 1);
            float py = oy + (float)(ww + 1) + (float)(n % 3 - 1);
            float flx = floorf(px), fly = floorf(py);
            float tlxf = fminf(fmaxf(flx,       0.f), 97.f);
            float tlyf = fminf(fmaxf(fly,       0.f), 97.f);
            float brxf = fminf(fmaxf(flx + 1.f, 0.f), 97.f);
            float bryf = fminf(fmaxf(fly + 1.f, 0.f), 97.f);
            float pcx  = fminf(fmaxf(px, 0.f), 97.f);
            float pcy  = fminf(fmaxf(py, 0.f), 97.f);
            float gx0 = 1.f + tlxf - pcx;
            float gx1 = 1.f - (brxf - pcx);
            float gy0 = 1.f + tlyf - pcy;
            float gy1 = 1.f - (bryf - pcy);
            int tlx = (int)tlxf, tly = (int)tlyf, brx = (int)brxf, bry = (int)bryf;
            int   qxs[4] = {tlx, tlx, brx, brx};
            int   qys[4] = {tly, bry, tly, bry};
            float gs[4]  = {gx0 * gy0, gx0 * gy1, gx1 * gy0, gx1 * gy1};
            int   idx[4]; float gg[4];
            #pragma unroll
            for (int c4 = 0; c4 < 4; ++c4) {
                bool okc = (qxs[c4] >= 1) && (qxs[c4] <= 96) && (qys[c4] >= 1) && (qys[c4] <= 96);
                idx[c4] = okc ? ((qxs[c4] - 1) * W_ + (qys[c4] - 1)) : 0;
                gg[c4]  = okc ? gs[c4] * mod : 0.f;
            }
            int4 iv;   iv.x = idx[0]; iv.y = idx[1]; iv.z = idx[2]; iv.w = idx[3];
            float4 gv; gv.x = gg[0];  gv.y = gg[1];  gv.z = gg[2];  gv.w = gg[3];
            *(int4*)  &s_meta[w][col * MSTR + n * 8]     = iv;
            *(float4*)&s_meta[w][col * MSTR + n * 8 + 4] = gv;
        }
    }
    __builtin_amdgcn_wave_barrier();

    // ---- phase 3: main GEMM, blend-after-MFMA ----
    floatx4 acc[4];
    #pragma unroll
    for (int mt = 0; mt < 4; ++mt) acc[mt] = (floatx4){0.f, 0.f, 0.f, 0.f};
    const floatx4 ZF = {0.f, 0.f, 0.f, 0.f};

    #pragma unroll 1
    for (int n = 0; n < 9; ++n) {
        int4   idx = *(const int4*)  &s_meta[w][col * MSTR + n * 8];
        float4 g4  = *(const float4*)&s_meta[w][col * MSTR + n * 8 + 4];
        bf16x8 af[4][2];
        #pragma unroll
        for (int mt = 0; mt < 4; ++mt)
            #pragma unroll
            for (int ksl = 0; ksl < 2; ++ksl)
                af[mt][ksl] = *(const bf16x8*)(wfm + ((size_t)((n * 2 + ksl) * 4 + mt) * 64 + lane) * 8);
        int   ixs[4] = {idx.x, idx.y, idx.z, idx.w};
        float gws[4] = {g4.x, g4.y, g4.z, g4.w};
        #pragma unroll
        for (int q = 0; q < 4; ++q) {
            const unsigned short* pq = xtb + (size_t)ixs[q] * 64 + q8;
            bf16x8 b0 = *(const bf16x8*)(pq);
            bf16x8 b1 = *(const bf16x8*)(pq + 32);
            floatx4 Y[4];
            #pragma unroll
            for (int mt = 0; mt < 4; ++mt)
                Y[mt] = __builtin_amdgcn_mfma_f32_16x16x32_bf16(af[mt][0], b0, ZF, 0, 0, 0);
            #pragma unroll
            for (int mt = 0; mt < 4; ++mt)
                Y[mt] = __builtin_amdgcn_mfma_f32_16x16x32_bf16(af[mt][1], b1, Y[mt], 0, 0, 0);
            float gq = gws[q];
            #pragma unroll
            for (int mt = 0; mt < 4; ++mt)
                #pragma unroll
                for (int r = 0; r < 4; ++r)
                    acc[mt][r] = fmaf(gq, Y[mt][r], acc[mt][r]);
        }
    }

    // ---- epilogue ----
    #pragma unroll
    for (int mt = 0; mt < 4; ++mt) {
        float4 cb4 = *(const float4*)&convb[mt * 16 + quad * 4];
        #pragma unroll
        for (int r = 0; r < 4; ++r) {
            int o = mt * 16 + quad * 4 + r;
            float bias = (r == 0) ? cb4.x : (r == 1) ? cb4.y : (r == 2) ? cb4.z : cb4.w;
            out[(size_t)(b * 64 + o) * HW_ + sb + col] = acc[mt][r] + bias;
        }
    }
}

// ---------------------------------------------------------------------------
extern "C" void kernel_launch(void* const* d_in, const int* in_sizes, int n_in,
                              void* d_out, int out_size, void* d_ws, size_t ws_size,
                              hipStream_t stream) {
    const float* x     = (const float*)d_in[0];
    const float* offw  = (const float*)d_in[1];
    const float* offb  = (const float*)d_in[2];
    const float* mw    = (const float*)d_in[3];
    const float* mb    = (const float*)d_in[4];
    const float* convw = (const float*)d_in[5];
    const float* convb = (const float*)d_in[6];
    char* ws = (char*)d_ws;
    unsigned short* xt16 = (unsigned short*)(ws + XT_OFF);
    unsigned short* wfm  = (unsigned short*)(ws + WFM_OFF);
    unsigned short* wfo  = (unsigned short*)(ws + WFO_OFF);
    float* out = (float*)d_out;

    k_pre  <<<dim3(1179), dim3(256), 0, stream>>>(x, offw, mw, convw, xt16, wfm, wfo);
    k_fused<<<dim3(2304), dim3(128), 0, stream>>>(xt16, wfo, wfm, offb, mb, convb, out);
}